// Round 3
// baseline (24933.537 us; speedup 1.0000x reference)
//
#include <hip/hip_runtime.h>

// AWD-LSTM forward, T=1024 B=64 DIN=512 H=1024.
// Round 7: geometry change for MALL-latency + traffic.
//  - 128 blocks x 1024 threads (16 waves = 4/SIMD): 4 batch-groups x
//    2 col-groups x 2 K-halves, LDS partial reduce. Per-step cache traffic
//    60 MB -> 36 MB; in-flight memory parallelism 4x per active CU.
//  - reset folded into state WRITE (h,c stored pre-zeroed for step t+1):
//    MFMA loop is a pure GEMM; hT/cT still written pre-reset.
//  - bf16 staging of Wh/Wi/x in ws (verified R6 win) unchanged.
// MODE 0: x+weights staged (~76.5MB ws); MODE 1: weights staged, x ping-pong
// (~12.7MB); MODE 2: raw fallback.

#define TT   1024
#define BB   64
#define DIN_ 512
#define HH   1024
#define BH   (BB * HH)    // 65536
#define BD   (BB * DIN_)  // 32768

typedef __attribute__((ext_vector_type(8))) short  short8;   // 8 bf16
typedef __attribute__((ext_vector_type(4))) float  floatx4;

__device__ __forceinline__ unsigned short f2bf(float f) {
    unsigned u = __builtin_bit_cast(unsigned, f);
    unsigned r = u + 0x7FFFu + ((u >> 16) & 1u);   // RNE
    return (unsigned short)(r >> 16);
}
__device__ __forceinline__ float b2f(unsigned short u) {
    return __builtin_bit_cast(float, (unsigned)u << 16);
}
// 8 consecutive fp32 -> bf16 fragment (order-preserving)
__device__ __forceinline__ short8 frag_f32(const float* __restrict__ p) {
    floatx4 f0 = *(const floatx4*)p;
    floatx4 f1 = *(const floatx4*)(p + 4);
    short8 a;
#pragma unroll
    for (int e = 0; e < 4; ++e) {
        a[e]     = (short)f2bf(f0[e]);
        a[e + 4] = (short)f2bf(f1[e]);
    }
    return a;
}
__device__ __forceinline__ float sigm(float x) { return 1.f / (1.f + __expf(-x)); }
// overflow-safe tanh: x->±inf => ±1, no NaN
__device__ __forceinline__ float ftanh(float x) {
    float e = __expf(2.f * x);
    return 1.f - 2.f / (e + 1.f);
}

// ---- ws layout (bytes) ----
#define WS_FLAG  0                    // int
#define WS_BSUM  1024                 // float[4096]        (16 KB)
#define WS_CWS   17408                // float[65536]       (256 KB)
#define WS_HBUF  279552               // ushort[2][65536]   (256 KB)
#define WS_WHB   541696               // ushort[4H*H]       (8 MB)
#define WS_WIB   8930304              // ushort[4H*DIN]     (4 MB)
#define WS_XTOP  13124608             // MODE0: ushort[T*BD] (64MB) / MODE1: ushort[2*BD]
#define NEED_COMPACT (13124608ull + 2ull * BD * 2ull)       // ~12.7 MB
#define NEED_FULL    (13124608ull + (size_t)TT * BD * 2ull) // ~76.5 MB

// Probe first 256 ushorts of Wi (uniform(+-2^-5)): bf16 -> ~100% exponent in
// [0x60,0x7B]; fp32-as-ushort -> ~55%.
__global__ __launch_bounds__(64) void dtype_probe(const unsigned short* __restrict__ wi_raw,
                                                  int* __restrict__ flag) {
    int lane = threadIdx.x;
    int pass = 0;
#pragma unroll
    for (int k = 0; k < 4; ++k) {
        unsigned e = (wi_raw[lane * 4 + k] >> 7) & 0xFF;
        pass += (e >= 0x60 && e <= 0x7B) ? 1 : 0;
    }
    for (int off = 32; off > 0; off >>= 1) pass += __shfl_down(pass, off);
    if (lane == 0) *flag = (pass >= 200) ? 1 : 0;
}

// init: h0 -> hbuf[0] bf16, c0 -> c_ws fp32, bi+bh -> bsum fp32,
//       (mode1) x_0 -> xpp[0] bf16
__global__ __launch_bounds__(256) void lstm_init(
    const void* __restrict__ h0, const void* __restrict__ c0,
    const void* __restrict__ bi, const void* __restrict__ bh,
    const void* __restrict__ x,
    const int* __restrict__ flag,
    unsigned short* __restrict__ hbuf0, float* __restrict__ c_ws,
    float* __restrict__ bsum, unsigned short* __restrict__ xpp,
    int stage_x0)
{
    const bool isbf = (*flag != 0);
    int i = blockIdx.x * 256 + threadIdx.x;    // 65536 threads
    hbuf0[i] = isbf ? ((const unsigned short*)h0)[i] : f2bf(((const float*)h0)[i]);
    c_ws[i]  = isbf ? b2f(((const unsigned short*)c0)[i]) : ((const float*)c0)[i];
    if (i < 4 * HH) {
        float vbi = isbf ? b2f(((const unsigned short*)bi)[i]) : ((const float*)bi)[i];
        float vbh = isbf ? b2f(((const unsigned short*)bh)[i]) : ((const float*)bh)[i];
        bsum[i] = vbi + vbh;
    }
    if (stage_x0 && i < BD / 8) {
        if (isbf) *(short8*)(xpp + (size_t)i * 8) =
                      *(const short8*)((const unsigned short*)x + (size_t)i * 8);
        else      *(short8*)(xpp + (size_t)i * 8) = frag_f32((const float*)x + (size_t)i * 8);
    }
}

// one-time staging: Wh, Wi (and optionally all of x) -> bf16 in ws
__global__ __launch_bounds__(256) void conv_ws(
    const void* __restrict__ Wh, const void* __restrict__ Wi,
    const void* __restrict__ x, const int* __restrict__ flag,
    unsigned short* __restrict__ whb, unsigned short* __restrict__ wib,
    unsigned short* __restrict__ xbf, int do_x)
{
    const bool isbf = (*flag != 0);
    const size_t NWH = (size_t)4 * HH * HH / 8;
    const size_t NWI = (size_t)4 * HH * DIN_ / 8;
    const size_t NX  = do_x ? (size_t)TT * BD / 8 : 0;
    const size_t total = NWH + NWI + NX;
    for (size_t i = (size_t)blockIdx.x * 256 + threadIdx.x; i < total;
         i += (size_t)gridDim.x * 256) {
        const void* src; unsigned short* dst; size_t off;
        if (i < NWH)            { src = Wh; dst = whb; off = i; }
        else if (i < NWH + NWI) { src = Wi; dst = wib; off = i - NWH; }
        else                    { src = x;  dst = xbf; off = i - NWH - NWI; }
        if (isbf) *(short8*)(dst + off * 8) =
                      *(const short8*)((const unsigned short*)src + off * 8);
        else      *(short8*)(dst + off * 8) = frag_f32((const float*)src + off * 8);
    }
}

// One timestep. 128 blocks x 1024 threads.
// Block covers jb = blockIdx.x*8 h-cols (x 4 gates = 32 output cols).
// 16 waves: bg = w&3 (batch 16-group), cg = (w>>2)&1 (col 16-group),
//           kh = w>>3 (K half). LDS partial reduce over kh.
template<int MODE>
__global__ __launch_bounds__(1024, 4) void lstm_step(
    const unsigned short* __restrict__ xb,    // MODE0: xbf[T*BD]; MODE1: xpp[2*BD]
    unsigned short* __restrict__ xpp_w,       // MODE1 writable
    const unsigned short* __restrict__ whb,   // [4H*H] bf16
    const unsigned short* __restrict__ wib,   // [4H*DIN] bf16
    const float* __restrict__ bsum,           // [4H] fp32 (bi+bh)
    const int*  __restrict__ tok,             // [T,B]
    unsigned short* __restrict__ hbuf,        // [2][B*H] bf16 (pre-reset-folded)
    float* __restrict__ c_ws,                 // [B*H] fp32 (pre-reset-folded)
    float* __restrict__ out,                  // fp32: [T,B,H] ++ hT ++ cT
    const void* __restrict__ xraw,
    const void* __restrict__ WiRaw,
    const void* __restrict__ WhRaw,
    const int*  __restrict__ flag,
    int t)
{
    const int tid  = threadIdx.x;
    const int w    = tid >> 6;
    const int lane = tid & 63;
    const int jb   = blockIdx.x * 8;

    const int bg = w & 3;
    const int cg = (w >> 2) & 1;
    const int kh = w >> 3;

    __shared__ float preact[2][64][33];

    // mfma_f32_16x16x32_bf16 lane maps (HW-verified):
    //   A: m=lane&15, k=(lane>>4)*8+j   B: n=lane&15, same k
    //   D: col=lane&15, row=(lane>>4)*4+r
    const int m    = lane & 15;
    const int colq = lane & 15;
    const int quad = lane >> 4;
    const int b_a  = bg * 16 + m;
    const int wrow = (colq >> 2) * HH + jb + cg * 4 + (colq & 3);

    floatx4 a0 = {0.f,0.f,0.f,0.f}, a1 = {0.f,0.f,0.f,0.f};
    floatx4 a2 = {0.f,0.f,0.f,0.f}, a3 = {0.f,0.f,0.f,0.f};

    // ---- h @ Wh^T : this wave's K-half (512 of 1024) ----
    const unsigned short* hsrc = hbuf + (size_t)(t & 1) * BH + b_a * HH + kh * 512 + quad * 8;
    if constexpr (MODE < 2) {
        const unsigned short* bp = whb + (size_t)wrow * HH + kh * 512 + quad * 8;
#pragma unroll
        for (int ki = 0; ki < 16; ki += 4) {
            a0 = __builtin_amdgcn_mfma_f32_16x16x32_bf16(*(const short8*)(hsrc + (ki+0)*32), *(const short8*)(bp + (ki+0)*32), a0, 0,0,0);
            a1 = __builtin_amdgcn_mfma_f32_16x16x32_bf16(*(const short8*)(hsrc + (ki+1)*32), *(const short8*)(bp + (ki+1)*32), a1, 0,0,0);
            a2 = __builtin_amdgcn_mfma_f32_16x16x32_bf16(*(const short8*)(hsrc + (ki+2)*32), *(const short8*)(bp + (ki+2)*32), a2, 0,0,0);
            a3 = __builtin_amdgcn_mfma_f32_16x16x32_bf16(*(const short8*)(hsrc + (ki+3)*32), *(const short8*)(bp + (ki+3)*32), a3, 0,0,0);
        }
    } else {
        const bool isbf = (*flag != 0);
        if (isbf) {
            const unsigned short* bp = (const unsigned short*)WhRaw + (size_t)wrow * HH + kh * 512 + quad * 8;
#pragma unroll
            for (int ki = 0; ki < 16; ki += 2) {
                a0 = __builtin_amdgcn_mfma_f32_16x16x32_bf16(*(const short8*)(hsrc + (ki+0)*32), *(const short8*)(bp + (ki+0)*32), a0, 0,0,0);
                a1 = __builtin_amdgcn_mfma_f32_16x16x32_bf16(*(const short8*)(hsrc + (ki+1)*32), *(const short8*)(bp + (ki+1)*32), a1, 0,0,0);
            }
        } else {
            const float* bp = (const float*)WhRaw + (size_t)wrow * HH + kh * 512 + quad * 8;
#pragma unroll
            for (int ki = 0; ki < 16; ki += 2) {
                a0 = __builtin_amdgcn_mfma_f32_16x16x32_bf16(*(const short8*)(hsrc + (ki+0)*32), frag_f32(bp + (ki+0)*32), a0, 0,0,0);
                a1 = __builtin_amdgcn_mfma_f32_16x16x32_bf16(*(const short8*)(hsrc + (ki+1)*32), frag_f32(bp + (ki+1)*32), a1, 0,0,0);
            }
        }
    }

    // ---- x_t @ Wi^T : this wave's K-half (256 of 512) ----
    if constexpr (MODE < 2) {
        const unsigned short* xsrc =
            (MODE == 0 ? xb + (size_t)t * BD : xb + (size_t)(t & 1) * BD)
            + b_a * DIN_ + kh * 256 + quad * 8;
        const unsigned short* ip = wib + (size_t)wrow * DIN_ + kh * 256 + quad * 8;
#pragma unroll
        for (int ki = 0; ki < 8; ki += 4) {
            a0 = __builtin_amdgcn_mfma_f32_16x16x32_bf16(*(const short8*)(xsrc + (ki+0)*32), *(const short8*)(ip + (ki+0)*32), a0, 0,0,0);
            a1 = __builtin_amdgcn_mfma_f32_16x16x32_bf16(*(const short8*)(xsrc + (ki+1)*32), *(const short8*)(ip + (ki+1)*32), a1, 0,0,0);
            a2 = __builtin_amdgcn_mfma_f32_16x16x32_bf16(*(const short8*)(xsrc + (ki+2)*32), *(const short8*)(ip + (ki+2)*32), a2, 0,0,0);
            a3 = __builtin_amdgcn_mfma_f32_16x16x32_bf16(*(const short8*)(xsrc + (ki+3)*32), *(const short8*)(ip + (ki+3)*32), a3, 0,0,0);
        }
    } else {
        const bool isbf = (*flag != 0);
        if (isbf) {
            const unsigned short* ap = (const unsigned short*)xraw + (size_t)t * BD + b_a * DIN_ + kh * 256 + quad * 8;
            const unsigned short* bp = (const unsigned short*)WiRaw + (size_t)wrow * DIN_ + kh * 256 + quad * 8;
#pragma unroll
            for (int ki = 0; ki < 8; ki += 2) {
                a0 = __builtin_amdgcn_mfma_f32_16x16x32_bf16(*(const short8*)(ap + (ki+0)*32), *(const short8*)(bp + (ki+0)*32), a0, 0,0,0);
                a1 = __builtin_amdgcn_mfma_f32_16x16x32_bf16(*(const short8*)(ap + (ki+1)*32), *(const short8*)(bp + (ki+1)*32), a1, 0,0,0);
            }
        } else {
            const float* ap = (const float*)xraw + (size_t)t * BD + b_a * DIN_ + kh * 256 + quad * 8;
            const float* bp = (const float*)WiRaw + (size_t)wrow * DIN_ + kh * 256 + quad * 8;
#pragma unroll
            for (int ki = 0; ki < 8; ki += 2) {
                a0 = __builtin_amdgcn_mfma_f32_16x16x32_bf16(frag_f32(ap + (ki+0)*32), frag_f32(bp + (ki+0)*32), a0, 0,0,0);
                a1 = __builtin_amdgcn_mfma_f32_16x16x32_bf16(frag_f32(ap + (ki+1)*32), frag_f32(bp + (ki+1)*32), a1, 0,0,0);
            }
        }
    }

    floatx4 s = (a0 + a1) + (a2 + a3);
#pragma unroll
    for (int r = 0; r < 4; ++r)
        preact[kh][bg * 16 + quad * 4 + r][cg * 16 + colq] = s[r];
    __syncthreads();

    // ---- cell epilogue: 512 threads, thread -> (b = tid>>3, jj = tid&7) ----
    if (tid < 512) {
        const int b   = tid >> 3;
        const int jj  = tid & 7;
        const int j   = jb + jj;           // (jj>>2)*4 + (jj&3) == jj
        const int cge = jj >> 2;
        const int jc  = jj & 3;

        float p[4];
#pragma unroll
        for (int q = 0; q < 4; ++q) {
            int pc = cge * 16 + q * 4 + jc;
            p[q] = preact[0][b][pc] + preact[1][b][pc] + bsum[q * HH + j];
        }
        float ig = sigm(p[0]);
        float fg = sigm(p[1]);
        float og = sigm(p[2]);
        float gg = ftanh(p[3]);            // g from LAST quarter (source quirk)

        float c_prev = c_ws[b * HH + j];   // already reset-folded at write
        float c_t    = fg * c_prev + ig * gg;
        float h_t    = og * ftanh(c_t);

        out[(size_t)t * BH + b * HH + j] = h_t;          // fp32, pre-reset

        // fold reset for step t+1: zero iff t>=1 && tok[t]==0
        float kn = (t >= 1 && tok[t * BB + b] == 0) ? 0.f : 1.f;
        c_ws[b * HH + j] = c_t * kn;
        hbuf[(size_t)((t + 1) & 1) * BH + b * HH + j] = f2bf(h_t * kn);

        if (t == TT - 1) {
            out[(size_t)TT * BH + b * HH + j]      = h_t;   // hT pre-reset
            out[(size_t)TT * BH + BH + b * HH + j] = c_t;   // cT pre-reset
        }
    } else if (MODE == 1 && tid < 544) {
        // stage x_{t+1} ping-pong (32 chunks/block), overlaps epilogue
        if (t < TT - 1) {
            const bool isbf = (*flag != 0);
            size_t ch = (size_t)blockIdx.x * 32 + (tid - 512);   // 4096 chunks
            unsigned short* dst = xpp_w + (size_t)((t + 1) & 1) * BD + ch * 8;
            if (isbf) *(short8*)dst =
                *(const short8*)((const unsigned short*)xraw + (size_t)(t + 1) * BD + ch * 8);
            else *(short8*)dst = frag_f32((const float*)xraw + (size_t)(t + 1) * BD + ch * 8);
        }
    }
}

extern "C" void kernel_launch(void* const* d_in, const int* in_sizes, int n_in,
                              void* d_out, int out_size, void* d_ws, size_t ws_size,
                              hipStream_t stream) {
    const void* x  = d_in[0];
    const void* h0 = d_in[1];
    const void* c0 = d_in[2];
    const void* Wi = d_in[3];
    const void* bi = d_in[4];
    const void* Wh = d_in[5];
    const void* bh = d_in[6];
    const int* tok = (const int*)d_in[7];
    float* out = (float*)d_out;

    char* ws = (char*)d_ws;
    int*            flag = (int*)(ws + WS_FLAG);
    float*          bsum = (float*)(ws + WS_BSUM);
    float*          c_ws = (float*)(ws + WS_CWS);
    unsigned short* hbuf = (unsigned short*)(ws + WS_HBUF);
    unsigned short* whb  = (unsigned short*)(ws + WS_WHB);
    unsigned short* wib  = (unsigned short*)(ws + WS_WIB);
    unsigned short* xtop = (unsigned short*)(ws + WS_XTOP);

    const int mode = (ws_size >= NEED_FULL) ? 0 : (ws_size >= NEED_COMPACT) ? 1 : 2;

    dtype_probe<<<1, 64, 0, stream>>>((const unsigned short*)Wi, flag);
    lstm_init<<<256, 256, 0, stream>>>(h0, c0, bi, bh, x, flag, hbuf, c_ws,
                                       bsum, xtop, (mode == 1) ? 1 : 0);
    if (mode < 2)
        conv_ws<<<2048, 256, 0, stream>>>(Wh, Wi, x, flag, whb, wib, xtop,
                                          (mode == 0) ? 1 : 0);

    for (int t = 0; t < TT; ++t) {
        if (mode == 0)
            lstm_step<0><<<128, 1024, 0, stream>>>(xtop, xtop, whb, wib, bsum, tok,
                                                   hbuf, c_ws, out, x, Wi, Wh, flag, t);
        else if (mode == 1)
            lstm_step<1><<<128, 1024, 0, stream>>>(xtop, xtop, whb, wib, bsum, tok,
                                                   hbuf, c_ws, out, x, Wi, Wh, flag, t);
        else
            lstm_step<2><<<128, 1024, 0, stream>>>(nullptr, nullptr, nullptr, nullptr,
                                                   bsum, tok, hbuf, c_ws, out,
                                                   x, Wi, Wh, flag, t);
    }
}

// Round 8
// 14872.359 us; speedup vs baseline: 1.6765x; 1.6765x over previous
//
#include <hip/hip_runtime.h>

// AWD-LSTM forward, T=1024 B=64 DIN=512 H=1024.
// Round 8 (4th resubmit; R4-R7 benches were GPUAcquisitionTimeout — never ran).
//  - 512 blocks x 256 threads: 2 blocks/CU, 8 waves/CU, ALL 256 CUs.
//    Block = 16 output cols x 32 batch rows; 4 waves = 2 batch-groups x
//    2 K-halves, LDS partial reduce (mechanism verified R7).
//    Per-CU stream 288 KB (< R6's 384 KB), 2x latency hiding.
//  - bf16 staging of Wh/Wi/x in ws (verified R6 win) unchanged.
//  - reset folded into state write (verified R7) retained.
// MODE 0: x+weights staged (~76.5MB ws); MODE 1: weights staged, x ping-pong
// (~12.7MB); MODE 2: raw fallback.

#define TT   1024
#define BB   64
#define DIN_ 512
#define HH   1024
#define BH   (BB * HH)    // 65536
#define BD   (BB * DIN_)  // 32768

typedef __attribute__((ext_vector_type(8))) short  short8;   // 8 bf16
typedef __attribute__((ext_vector_type(4))) float  floatx4;

__device__ __forceinline__ unsigned short f2bf(float f) {
    unsigned u = __builtin_bit_cast(unsigned, f);
    unsigned r = u + 0x7FFFu + ((u >> 16) & 1u);   // RNE
    return (unsigned short)(r >> 16);
}
__device__ __forceinline__ float b2f(unsigned short u) {
    return __builtin_bit_cast(float, (unsigned)u << 16);
}
// 8 consecutive fp32 -> bf16 fragment (order-preserving)
__device__ __forceinline__ short8 frag_f32(const float* __restrict__ p) {
    floatx4 f0 = *(const floatx4*)p;
    floatx4 f1 = *(const floatx4*)(p + 4);
    short8 a;
#pragma unroll
    for (int e = 0; e < 4; ++e) {
        a[e]     = (short)f2bf(f0[e]);
        a[e + 4] = (short)f2bf(f1[e]);
    }
    return a;
}
__device__ __forceinline__ float sigm(float x) { return 1.f / (1.f + __expf(-x)); }
// overflow-safe tanh: x->±inf => ±1, no NaN
__device__ __forceinline__ float ftanh(float x) {
    float e = __expf(2.f * x);
    return 1.f - 2.f / (e + 1.f);
}

// ---- ws layout (bytes) ----
#define WS_FLAG  0                    // int
#define WS_BSUM  1024                 // float[4096]        (16 KB)
#define WS_CWS   17408                // float[65536]       (256 KB)
#define WS_HBUF  279552               // ushort[2][65536]   (256 KB)
#define WS_WHB   541696               // ushort[4H*H]       (8 MB)
#define WS_WIB   8930304              // ushort[4H*DIN]     (4 MB)
#define WS_XTOP  13124608             // MODE0: ushort[T*BD] (64MB) / MODE1: ushort[2*BD]
#define NEED_COMPACT (13124608ull + 2ull * BD * 2ull)       // ~12.7 MB
#define NEED_FULL    (13124608ull + (size_t)TT * BD * 2ull) // ~76.5 MB

// Probe first 256 ushorts of Wi (uniform(+-2^-5)): bf16 -> ~100% exponent in
// [0x60,0x7B]; fp32-as-ushort -> ~55%.
__global__ __launch_bounds__(64) void dtype_probe(const unsigned short* __restrict__ wi_raw,
                                                  int* __restrict__ flag) {
    int lane = threadIdx.x;
    int pass = 0;
#pragma unroll
    for (int k = 0; k < 4; ++k) {
        unsigned e = (wi_raw[lane * 4 + k] >> 7) & 0xFF;
        pass += (e >= 0x60 && e <= 0x7B) ? 1 : 0;
    }
    for (int off = 32; off > 0; off >>= 1) pass += __shfl_down(pass, off);
    if (lane == 0) *flag = (pass >= 200) ? 1 : 0;
}

// init: h0 -> hbuf[0] bf16, c0 -> c_ws fp32, bi+bh -> bsum fp32,
//       (mode1) x_0 -> xpp[0] bf16
__global__ __launch_bounds__(256) void lstm_init(
    const void* __restrict__ h0, const void* __restrict__ c0,
    const void* __restrict__ bi, const void* __restrict__ bh,
    const void* __restrict__ x,
    const int* __restrict__ flag,
    unsigned short* __restrict__ hbuf0, float* __restrict__ c_ws,
    float* __restrict__ bsum, unsigned short* __restrict__ xpp,
    int stage_x0)
{
    const bool isbf = (*flag != 0);
    int i = blockIdx.x * 256 + threadIdx.x;    // 65536 threads
    hbuf0[i] = isbf ? ((const unsigned short*)h0)[i] : f2bf(((const float*)h0)[i]);
    c_ws[i]  = isbf ? b2f(((const unsigned short*)c0)[i]) : ((const float*)c0)[i];
    if (i < 4 * HH) {
        float vbi = isbf ? b2f(((const unsigned short*)bi)[i]) : ((const float*)bi)[i];
        float vbh = isbf ? b2f(((const unsigned short*)bh)[i]) : ((const float*)bh)[i];
        bsum[i] = vbi + vbh;
    }
    if (stage_x0 && i < BD / 8) {
        if (isbf) *(short8*)(xpp + (size_t)i * 8) =
                      *(const short8*)((const unsigned short*)x + (size_t)i * 8);
        else      *(short8*)(xpp + (size_t)i * 8) = frag_f32((const float*)x + (size_t)i * 8);
    }
}

// one-time staging: Wh, Wi (and optionally all of x) -> bf16 in ws
__global__ __launch_bounds__(256) void conv_ws(
    const void* __restrict__ Wh, const void* __restrict__ Wi,
    const void* __restrict__ x, const int* __restrict__ flag,
    unsigned short* __restrict__ whb, unsigned short* __restrict__ wib,
    unsigned short* __restrict__ xbf, int do_x)
{
    const bool isbf = (*flag != 0);
    const size_t NWH = (size_t)4 * HH * HH / 8;
    const size_t NWI = (size_t)4 * HH * DIN_ / 8;
    const size_t NX  = do_x ? (size_t)TT * BD / 8 : 0;
    const size_t total = NWH + NWI + NX;
    for (size_t i = (size_t)blockIdx.x * 256 + threadIdx.x; i < total;
         i += (size_t)gridDim.x * 256) {
        const void* src; unsigned short* dst; size_t off;
        if (i < NWH)            { src = Wh; dst = whb; off = i; }
        else if (i < NWH + NWI) { src = Wi; dst = wib; off = i - NWH; }
        else                    { src = x;  dst = xbf; off = i - NWH - NWI; }
        if (isbf) *(short8*)(dst + off * 8) =
                      *(const short8*)((const unsigned short*)src + off * 8);
        else      *(short8*)(dst + off * 8) = frag_f32((const float*)src + off * 8);
    }
}

// One timestep. 512 blocks x 256 threads (2 blocks/CU, 8 waves/CU).
// Block: bh2 = blockIdx.x>>8 (batch half), jb = (blockIdx.x&255)*4 h-cols.
// Waves: bg = w&1 (16-batch group within half), kh = w>>1 (K half).
// preact[2][32][17] LDS partial reduce over kh.
template<int MODE>
__global__ __launch_bounds__(256, 2) void lstm_step(
    const unsigned short* __restrict__ xb,    // MODE0: xbf[T*BD]; MODE1: xpp[2*BD]
    unsigned short* __restrict__ xpp_w,       // MODE1 writable
    const unsigned short* __restrict__ whb,   // [4H*H] bf16
    const unsigned short* __restrict__ wib,   // [4H*DIN] bf16
    const float* __restrict__ bsum,           // [4H] fp32 (bi+bh)
    const int*  __restrict__ tok,             // [T,B]
    unsigned short* __restrict__ hbuf,        // [2][B*H] bf16 (reset-folded)
    float* __restrict__ c_ws,                 // [B*H] fp32 (reset-folded)
    float* __restrict__ out,                  // fp32: [T,B,H] ++ hT ++ cT
    const void* __restrict__ xraw,
    const void* __restrict__ WiRaw,
    const void* __restrict__ WhRaw,
    const int*  __restrict__ flag,
    int t)
{
    const int tid  = threadIdx.x;
    const int w    = tid >> 6;
    const int lane = tid & 63;
    const int bh2  = blockIdx.x >> 8;          // batch half (0/1)
    const int jb   = (blockIdx.x & 255) * 4;   // h-col group

    const int bg = w & 1;    // batch 16-group within the half
    const int kh = w >> 1;   // K half

    __shared__ float preact[2][32][17];

    // mfma_f32_16x16x32_bf16 lane maps (HW-verified):
    //   A: m=lane&15, k=(lane>>4)*8+j   B: n=lane&15, same k
    //   D: col=lane&15, row=(lane>>4)*4+r
    const int m    = lane & 15;
    const int colq = lane & 15;
    const int quad = lane >> 4;
    const int b_a  = bh2 * 32 + bg * 16 + m;              // batch row (A)
    const int wrow = (colq >> 2) * HH + jb + (colq & 3);  // weight row (B col n)

    floatx4 a0 = {0.f,0.f,0.f,0.f}, a1 = {0.f,0.f,0.f,0.f};
    floatx4 a2 = {0.f,0.f,0.f,0.f}, a3 = {0.f,0.f,0.f,0.f};

    // ---- h @ Wh^T : this wave's K-half (512 of 1024), 16 iters ----
    const unsigned short* hsrc = hbuf + (size_t)(t & 1) * BH + b_a * HH + kh * 512 + quad * 8;
    if constexpr (MODE < 2) {
        const unsigned short* bp = whb + (size_t)wrow * HH + kh * 512 + quad * 8;
#pragma unroll
        for (int ki = 0; ki < 16; ki += 4) {
            a0 = __builtin_amdgcn_mfma_f32_16x16x32_bf16(*(const short8*)(hsrc + (ki+0)*32), *(const short8*)(bp + (ki+0)*32), a0, 0,0,0);
            a1 = __builtin_amdgcn_mfma_f32_16x16x32_bf16(*(const short8*)(hsrc + (ki+1)*32), *(const short8*)(bp + (ki+1)*32), a1, 0,0,0);
            a2 = __builtin_amdgcn_mfma_f32_16x16x32_bf16(*(const short8*)(hsrc + (ki+2)*32), *(const short8*)(bp + (ki+2)*32), a2, 0,0,0);
            a3 = __builtin_amdgcn_mfma_f32_16x16x32_bf16(*(const short8*)(hsrc + (ki+3)*32), *(const short8*)(bp + (ki+3)*32), a3, 0,0,0);
        }
    } else {
        const bool isbf = (*flag != 0);
        if (isbf) {
            const unsigned short* bp = (const unsigned short*)WhRaw + (size_t)wrow * HH + kh * 512 + quad * 8;
#pragma unroll
            for (int ki = 0; ki < 16; ki += 2) {
                a0 = __builtin_amdgcn_mfma_f32_16x16x32_bf16(*(const short8*)(hsrc + (ki+0)*32), *(const short8*)(bp + (ki+0)*32), a0, 0,0,0);
                a1 = __builtin_amdgcn_mfma_f32_16x16x32_bf16(*(const short8*)(hsrc + (ki+1)*32), *(const short8*)(bp + (ki+1)*32), a1, 0,0,0);
            }
        } else {
            const float* bp = (const float*)WhRaw + (size_t)wrow * HH + kh * 512 + quad * 8;
#pragma unroll
            for (int ki = 0; ki < 16; ki += 2) {
                a0 = __builtin_amdgcn_mfma_f32_16x16x32_bf16(*(const short8*)(hsrc + (ki+0)*32), frag_f32(bp + (ki+0)*32), a0, 0,0,0);
                a1 = __builtin_amdgcn_mfma_f32_16x16x32_bf16(*(const short8*)(hsrc + (ki+1)*32), frag_f32(bp + (ki+1)*32), a1, 0,0,0);
            }
        }
    }

    // ---- x_t @ Wi^T : this wave's K-half (256 of 512), 8 iters ----
    if constexpr (MODE < 2) {
        const unsigned short* xsrc =
            (MODE == 0 ? xb + (size_t)t * BD : xb + (size_t)(t & 1) * BD)
            + b_a * DIN_ + kh * 256 + quad * 8;
        const unsigned short* ip = wib + (size_t)wrow * DIN_ + kh * 256 + quad * 8;
#pragma unroll
        for (int ki = 0; ki < 8; ki += 4) {
            a0 = __builtin_amdgcn_mfma_f32_16x16x32_bf16(*(const short8*)(xsrc + (ki+0)*32), *(const short8*)(ip + (ki+0)*32), a0, 0,0,0);
            a1 = __builtin_amdgcn_mfma_f32_16x16x32_bf16(*(const short8*)(xsrc + (ki+1)*32), *(const short8*)(ip + (ki+1)*32), a1, 0,0,0);
            a2 = __builtin_amdgcn_mfma_f32_16x16x32_bf16(*(const short8*)(xsrc + (ki+2)*32), *(const short8*)(ip + (ki+2)*32), a2, 0,0,0);
            a3 = __builtin_amdgcn_mfma_f32_16x16x32_bf16(*(const short8*)(xsrc + (ki+3)*32), *(const short8*)(ip + (ki+3)*32), a3, 0,0,0);
        }
    } else {
        const bool isbf = (*flag != 0);
        if (isbf) {
            const unsigned short* ap = (const unsigned short*)xraw + (size_t)t * BD + b_a * DIN_ + kh * 256 + quad * 8;
            const unsigned short* bp = (const unsigned short*)WiRaw + (size_t)wrow * DIN_ + kh * 256 + quad * 8;
#pragma unroll
            for (int ki = 0; ki < 8; ki += 2) {
                a0 = __builtin_amdgcn_mfma_f32_16x16x32_bf16(*(const short8*)(ap + (ki+0)*32), *(const short8*)(bp + (ki+0)*32), a0, 0,0,0);
                a1 = __builtin_amdgcn_mfma_f32_16x16x32_bf16(*(const short8*)(ap + (ki+1)*32), *(const short8*)(bp + (ki+1)*32), a1, 0,0,0);
            }
        } else {
            const float* ap = (const float*)xraw + (size_t)t * BD + b_a * DIN_ + kh * 256 + quad * 8;
            const float* bp = (const float*)WiRaw + (size_t)wrow * DIN_ + kh * 256 + quad * 8;
#pragma unroll
            for (int ki = 0; ki < 8; ki += 2) {
                a0 = __builtin_amdgcn_mfma_f32_16x16x32_bf16(frag_f32(ap + (ki+0)*32), frag_f32(bp + (ki+0)*32), a0, 0,0,0);
                a1 = __builtin_amdgcn_mfma_f32_16x16x32_bf16(frag_f32(ap + (ki+1)*32), frag_f32(bp + (ki+1)*32), a1, 0,0,0);
            }
        }
    }

    floatx4 s = (a0 + a1) + (a2 + a3);
#pragma unroll
    for (int r = 0; r < 4; ++r)
        preact[kh][bg * 16 + quad * 4 + r][colq] = s[r];
    __syncthreads();

    // ---- cell epilogue: 128 threads -> (lb = tid>>2 in [0,32), jj = tid&3) ----
    if (tid < 128) {
        const int lb = tid >> 2;
        const int jj = tid & 3;
        const int b  = bh2 * 32 + lb;
        const int j  = jb + jj;

        float p[4];
#pragma unroll
        for (int q = 0; q < 4; ++q) {
            int pc = q * 4 + jj;
            p[q] = preact[0][lb][pc] + preact[1][lb][pc] + bsum[q * HH + j];
        }
        float ig = sigm(p[0]);
        float fg = sigm(p[1]);
        float og = sigm(p[2]);
        float gg = ftanh(p[3]);            // g from LAST quarter (source quirk)

        float c_prev = c_ws[b * HH + j];   // already reset-folded at write
        float c_t    = fg * c_prev + ig * gg;
        float h_t    = og * ftanh(c_t);

        out[(size_t)t * BH + b * HH + j] = h_t;          // fp32, pre-reset

        // fold reset for step t+1: zero iff t>=1 && tok[t]==0
        float kn = (t >= 1 && tok[t * BB + b] == 0) ? 0.f : 1.f;
        c_ws[b * HH + j] = c_t * kn;
        hbuf[(size_t)((t + 1) & 1) * BH + b * HH + j] = f2bf(h_t * kn);

        if (t == TT - 1) {
            out[(size_t)TT * BH + b * HH + j]      = h_t;   // hT pre-reset
            out[(size_t)TT * BH + BH + b * HH + j] = c_t;   // cT pre-reset
        }
    } else if (MODE == 1 && tid < 136) {
        // stage x_{t+1} ping-pong (8 chunks/block x 512 blocks = 4096 = BD/8)
        if (t < TT - 1) {
            const bool isbf = (*flag != 0);
            size_t ch = (size_t)blockIdx.x * 8 + (tid - 128);
            unsigned short* dst = xpp_w + (size_t)((t + 1) & 1) * BD + ch * 8;
            if (isbf) *(short8*)dst =
                *(const short8*)((const unsigned short*)xraw + (size_t)(t + 1) * BD + ch * 8);
            else *(short8*)dst = frag_f32((const float*)xraw + (size_t)(t + 1) * BD + ch * 8);
        }
    }
}

extern "C" void kernel_launch(void* const* d_in, const int* in_sizes, int n_in,
                              void* d_out, int out_size, void* d_ws, size_t ws_size,
                              hipStream_t stream) {
    const void* x  = d_in[0];
    const void* h0 = d_in[1];
    const void* c0 = d_in[2];
    const void* Wi = d_in[3];
    const void* bi = d_in[4];
    const void* Wh = d_in[5];
    const void* bh = d_in[6];
    const int* tok = (const int*)d_in[7];
    float* out = (float*)d_out;

    char* ws = (char*)d_ws;
    int*            flag = (int*)(ws + WS_FLAG);
    float*          bsum = (float*)(ws + WS_BSUM);
    float*          c_ws = (float*)(ws + WS_CWS);
    unsigned short* hbuf = (unsigned short*)(ws + WS_HBUF);
    unsigned short* whb  = (unsigned short*)(ws + WS_WHB);
    unsigned short* wib  = (unsigned short*)(ws + WS_WIB);
    unsigned short* xtop = (unsigned short*)(ws + WS_XTOP);

    const int mode = (ws_size >= NEED_FULL) ? 0 : (ws_size >= NEED_COMPACT) ? 1 : 2;

    dtype_probe<<<1, 64, 0, stream>>>((const unsigned short*)Wi, flag);
    lstm_init<<<256, 256, 0, stream>>>(h0, c0, bi, bh, x, flag, hbuf, c_ws,
                                       bsum, xtop, (mode == 1) ? 1 : 0);
    if (mode < 2)
        conv_ws<<<2048, 256, 0, stream>>>(Wh, Wi, x, flag, whb, wib, xtop,
                                          (mode == 0) ? 1 : 0);

    for (int t = 0; t < TT; ++t) {
        if (mode == 0)
            lstm_step<0><<<512, 256, 0, stream>>>(xtop, xtop, whb, wib, bsum, tok,
                                                  hbuf, c_ws, out, x, Wi, Wh, flag, t);
        else if (mode == 1)
            lstm_step<1><<<512, 256, 0, stream>>>(xtop, xtop, whb, wib, bsum, tok,
                                                  hbuf, c_ws, out, x, Wi, Wh, flag, t);
        else
            lstm_step<2><<<512, 256, 0, stream>>>(nullptr, nullptr, nullptr, nullptr,
                                                  bsum, tok, hbuf, c_ws, out,
                                                  x, Wi, Wh, flag, t);
    }
}